// Round 9
// baseline (77.615 us; speedup 1.0000x reference)
//
#include <hip/hip_runtime.h>
#include <math.h>

// Problem constants: B*T = 32768 rows, C=1, V=256, K=512 codes.
#define NV 256
#define NK 512
#define TSH 4096      // shorts per 16-code tile (16 codes * 256 dims, bf16)
#define SLABR 128     // rows per slab (8 x-tiles of 16)

typedef unsigned short u16;
typedef unsigned int u32;
using short8  = __attribute__((ext_vector_type(8))) short;
using floatx4 = __attribute__((ext_vector_type(4))) float;

// fp32 -> bf16 round-to-nearest-even.
__device__ __forceinline__ u16 f2bf(float f) {
    unsigned int u = __float_as_uint(f);
    u += 0x7fffu + ((u >> 16) & 1u);
    return (u16)(u >> 16);
}
__device__ __forceinline__ floatx4 mfma16(short8 a, short8 b, floatx4 c) {
    return __builtin_amdgcn_mfma_f32_16x16x32_bf16(a, b, c, 0, 0, 0);
}

// Kernel 0: per-code esq(+2.0 bias: keys provably positive), bf16 codebook
// packed in MFMA order shorts[tile][kc][code][8]; zero hist/counter; init
// idx_ws to all-ones (atomicMin identity). Grid 128x256 = 32768 threads.
__global__ __launch_bounds__(256) void vq_prepcvt(const float* __restrict__ emb,
                                                  float* __restrict__ esq1,
                                                  u16* __restrict__ ehws,
                                                  int* __restrict__ hist,
                                                  int* __restrict__ counter,
                                                  u32* __restrict__ idx_ws) {
    const int t = threadIdx.x;
    const int lane = t & 63;
    const int code = blockIdx.x * 4 + (t >> 6);   // one wave per code
    const int nt = code >> 4, c = code & 15;
    const float4 v = *(const float4*)(emb + (size_t)code * NV + lane * 4);
    ushort4 h;
    h.x = f2bf(v.x);
    h.y = f2bf(v.y);
    h.z = f2bf(v.z);
    h.w = f2bf(v.w);
    // dim base = lane*4 -> kchunk8 = lane>>1, j0 = (lane&1)*4
    const size_t base = (size_t)nt * TSH + (size_t)(lane >> 1) * 128 + c * 8 + (lane & 1) * 4;
    *(ushort4*)(ehws + base) = h;
    float s = v.x * v.x + v.y * v.y + v.z * v.z + v.w * v.w;
#pragma unroll
    for (int m = 1; m <= 32; m <<= 1) s += __shfl_xor(s, m, 64);
    if (lane == 0) esq1[code] = s + 2.0f;
    const int g = blockIdx.x * 256 + t;
    if (g < NK) hist[g] = 0;
    if (g == 0) *counter = 0;
    idx_ws[g] = 0xffffffffu;    // g covers all 32768 rows exactly
}

// Kernel 1: code-stationary nearest-code search.
// Block = 1024 threads = 16 waves; wave w holds codes of tile (half*16+w)
// in registers forever. Grid = 2*slabs = 512: block (slab s, half h)
// streams s's 8 x-tiles (16 rows each) through LDS (bf16, XOR-swizzled),
// computes 16x256 distance keys per tile, and publishes per-row winners
// via global atomicMin on u32 keys (deterministic; code in low 9 bits).
__global__ __launch_bounds__(1024, 4) void vq_search(
    const float* __restrict__ x,
    const u16* __restrict__ ehws,
    const float* __restrict__ esq1,
    u32* __restrict__ idx_ws) {
    __shared__ u16 xl[2][16 * NV];        // 16 KB: double-buffered bf16 x-tile
    __shared__ u32 kmin[2][16][16];       // [buf][wave][row] per-tile winners

    const int t = threadIdx.x;
    const int wid = t >> 6;               // wave = 0..15 (also: staged row)
    const int lane = t & 63;
    const int lr = lane & 15;
    const int lg = lane >> 4;
    const int slab = blockIdx.x >> 1;
    const int half = blockIdx.x & 1;
    const size_t row0 = (size_t)slab * SLABR;

    // ---- stationary B: this wave's 16 codes (tile nt), plus their esq ----
    const int nt = half * 16 + wid;       // code tile 0..31
    const u16* bb = ehws + (size_t)nt * TSH + lane * 8;
    short8 bw[8];
#pragma unroll
    for (int ks = 0; ks < 8; ++ks) bw[ks] = *(const short8*)(bb + ks * 512);
    const float evq = esq1[nt * 16 + lr];           // esq + 2.0 for code lr
    const u32 codeid = (u32)(nt * 16 + lr);

    // ---- stage x-tile 0: wave w loads row w (fp32), converts, ds_writes ----
#define XSTAGE_LOAD(XR, TAU)                                                   \
    XR = *(const float4*)(x + (row0 + (TAU) * 16 + wid) * NV + lane * 4)
#define XSTAGE_WRITE(XR, BUF) do {                                             \
        u32 lo = (u32)f2bf(XR.x) | ((u32)f2bf(XR.y) << 16);                    \
        u32 hi = (u32)f2bf(XR.z) | ((u32)f2bf(XR.w) << 16);                    \
        int byte = wid * 512 + ((lane * 8) ^ ((wid & 7) << 4));                \
        *(uint2*)((char*)&xl[BUF][0] + byte) = make_uint2(lo, hi);             \
    } while (0)

    float4 xr;
    XSTAGE_LOAD(xr, 0);
    XSTAGE_WRITE(xr, 0);
    __syncthreads();

    // ---- 8 phases: MFMA on buf, prefetch tile+1 into buf^1 ----
    for (int tau = 0; tau < 8; ++tau) {
        const int buf = tau & 1;
        if (tau < 7) XSTAGE_LOAD(xr, tau + 1);     // issue early (T14)

        floatx4 acc = {0.f, 0.f, 0.f, 0.f};
#pragma unroll
        for (int ks = 0; ks < 8; ++ks) {
            // A-frag: row lr, dims ks*32+lg*8.. ; same XOR swizzle as write
            int byte = lr * 512 + ((ks * 64 + lg * 16) ^ ((lr & 7) << 4));
            short8 a = *(const short8*)((const char*)&xl[buf][0] + byte);
            acc = mfma16(a, bw[ks], acc);
        }
        u32 rmin[4];
#pragma unroll
        for (int j = 0; j < 4; ++j) {
            // d+2 = (esq+2) - 2*cross > 0 -> raw float bits monotone
            float d = fmaf(-2.0f, acc[j], evq);
            rmin[j] = (__float_as_uint(d) & 0xfffffe00u) | codeid;
        }
        // min over this wave's 16 codes (low 4 lane bits)
#pragma unroll
        for (int j = 0; j < 4; ++j) {
#pragma unroll
            for (int m = 1; m <= 8; m <<= 1) {
                u32 v = (u32)__shfl_xor((int)rmin[j], m, 64);
                rmin[j] = min(rmin[j], v);
            }
        }
        if (lr == 0) {
#pragma unroll
            for (int j = 0; j < 4; ++j) kmin[buf][wid][lg * 4 + j] = rmin[j];
        }

        if (tau < 7) XSTAGE_WRITE(xr, buf ^ 1);    // write late (T14)
        __syncthreads();

        // combine tile tau's winners across the block's 16 waves (waves 0-3)
        if (t < 256) {
            const int r = t >> 4, w2 = t & 15;
            u32 v = kmin[buf][w2][r];
#pragma unroll
            for (int m = 1; m <= 8; m <<= 1) {
                u32 o = (u32)__shfl_xor((int)v, m, 64);
                v = min(v, o);
            }
            if (w2 == 0) atomicMin(&idx_ws[row0 + tau * 16 + r], v);
        }
    }
#undef XSTAGE_LOAD
#undef XSTAGE_WRITE
}

// Kernel 2: epilogue — gather e[idx], straight-through out0, loss sums,
// histogram; fused entropy via last-block election (R7-proven pattern).
__global__ __launch_bounds__(256) void vq_epi(
    const float* __restrict__ x,
    const float* __restrict__ emb,
    const u32* __restrict__ idx_ws,
    int* __restrict__ hist,
    int* __restrict__ counter,
    float* __restrict__ out0,
    float* __restrict__ out1,
    float* __restrict__ out2,
    float* __restrict__ ent,
    int n_rows) {
    __shared__ float sred[NK];
    __shared__ int s_last;

    const int t = threadIdx.x;
    const int wid = t >> 6;
    const int lane = t & 63;
    const size_t rbase = ((size_t)blockIdx.x * 4 + wid) * 16;

    for (int rr = 0; rr < 16; ++rr) {
        const size_t row = rbase + rr;
        const int idx = (int)(idx_ws[row] & 511u);
        const float4 xv = *(const float4*)(x + row * NV + lane * 4);
        const float4 ev = *(const float4*)(emb + (size_t)idx * NV + lane * 4);
        float4 o;
        o.x = (ev.x - xv.x) + xv.x;
        o.y = (ev.y - xv.y) + xv.y;
        o.z = (ev.z - xv.z) + xv.z;
        o.w = (ev.w - xv.w) + xv.w;
        *(float4*)(out0 + row * NV + lane * 4) = o;
        float d0 = xv.x - ev.x, d1 = xv.y - ev.y, d2 = xv.z - ev.z, d3 = xv.w - ev.w;
        float s = d0 * d0 + d1 * d1 + d2 * d2 + d3 * d3;
#pragma unroll
        for (int m = 1; m <= 32; m <<= 1) s += __shfl_xor(s, m, 64);
        if (lane == 0) {
            out1[row] = s;
            out2[row] = s;
            atomicAdd(&hist[idx], 1);
        }
    }
    __syncthreads();
    if (t == 0) {
        __threadfence();
        s_last = (atomicAdd(counter, 1) == (int)gridDim.x - 1);
    }
    __syncthreads();
    if (s_last) {
        const float invn = 1.0f / (float)n_rows;
        float local = 0.0f;
        for (int k = t; k < NK; k += 256) {
            int h = atomicAdd(&hist[k], 0);   // device-coherent read
            if (h > 0) {
                float p = (float)h * invn;
                local += p * logf(p);
            }
        }
        sred[t] = local;
        __syncthreads();
        for (int s = 128; s >= 1; s >>= 1) {
            if (t < s) sred[t] += sred[t + s];
            __syncthreads();
        }
        if (t == 0) *ent = -sred[0];
    }
}

extern "C" void kernel_launch(void* const* d_in, const int* in_sizes, int n_in,
                              void* d_out, int out_size, void* d_ws, size_t ws_size,
                              hipStream_t stream) {
    const float* x   = (const float*)d_in[0];   // (B,T,1,256) fp32
    const float* emb = (const float*)d_in[1];   // (1,512,256) fp32

    const int n_rows = in_sizes[0] / NV;        // 32768

    float* out0 = (float*)d_out;
    float* out1 = out0 + (size_t)n_rows * NV;
    float* out2 = out1 + n_rows;
    float* ent  = out2 + n_rows;

    // ws: esq+2 (2KB) | hist (2KB) | counter (16B) | idx_ws (128KB) | bf16 codebook (256KB)
    float* esq1  = (float*)d_ws;
    int* hist    = (int*)(esq1 + NK);
    int* counter = hist + NK;
    u32* idx_ws  = (u32*)(counter + 4);
    u16* ehws    = (u16*)(idx_ws + n_rows);

    const int slabs = n_rows / SLABR;           // 256

    vq_prepcvt<<<NK / 4, 256, 0, stream>>>(emb, esq1, ehws, hist, counter, idx_ws);
    vq_search<<<slabs * 2, 1024, 0, stream>>>(x, ehws, esq1, idx_ws);
    vq_epi<<<n_rows / 64, 256, 0, stream>>>(x, emb, idx_ws, hist, counter,
                                            out0, out1, out2, ent, n_rows);
}